// Round 9
// baseline (118.269 us; speedup 1.0000x reference)
//
#include <hip/hip_runtime.h>

typedef __attribute__((ext_vector_type(8))) short          short8_t;   // 8 bf16
typedef __attribute__((ext_vector_type(8))) unsigned short ushort8_t;
typedef __attribute__((ext_vector_type(4))) float          floatx4;

constexpr int N_ROWS  = 8192;
constexpr int DIM     = 64;
constexpr int PFRAG   = 128 * DIM;            // 8192 ushorts per hi/lo section
constexpr int PSTRIDE = 2 * PFRAG + 4096;     // + tail section (8 groups x 512)
constexpr unsigned short ONE_BF16 = 0x3F80;

// f32 -> bf16 round-to-nearest-even
__device__ __forceinline__ unsigned short bf16_rne(float f) {
    unsigned int u = __float_as_uint(f);
    u += 0x7FFFu + ((u >> 16) & 1u);
    return (unsigned short)(u >> 16);
}
__device__ __forceinline__ float bf16_val(unsigned short h) {
    return __uint_as_float((unsigned int)h << 16);
}

// ---------------------------------------------------------------------------
// Kernel 1: augmented-K panels, fragment-ordered.
// X panel: hi = bf16(2x), lo = bf16(2x - hi); tail frag (k-step 6, lg==0):
//   [-x2h, -x2l, 1, 1, 0...] so that sum over augmented K gives
//   acc = 2*x.y - x2 - y2 = -dist2 directly.
// Y panel: hi/lo of y; tail = [1, 1, -y2h, -y2l, 0...].
// Layout per panel: hi[8192] lo[8192] tail[4096] ushorts (40 KiB).
// Fragment offset (hi/lo): ((g*2 + ks)*64 + lg*16 + li)*8 + e, k = ks*32+lg*8+e.
// Tail offset: 2*PFRAG + g*512 + (lg*16 + li)*8.
// Two threads per row (h = k-half); norms combined via shfl_xor.
// ---------------------------------------------------------------------------
__global__ void __launch_bounds__(256)
split_norms_kernel(const float* __restrict__ X, const float* __restrict__ Y,
                   unsigned short* __restrict__ Xs, unsigned short* __restrict__ Ys) {
    const int t  = blockIdx.x * 256 + threadIdx.x;   // [0, 16384)
    const int r  = t >> 1;                           // row
    const int h  = t & 1;                            // k-half (== ks)
    const int p  = r >> 7;
    const int rl = r & 127;
    const int g  = rl >> 4;
    const int li = rl & 15;
    const size_t pb = (size_t)p * PSTRIDE;

    const float4* xr = reinterpret_cast<const float4*>(X + (size_t)r * DIM + h * 32);
    const float4* yr = reinterpret_cast<const float4*>(Y + (size_t)r * DIM + h * 32);

    float sx = 0.f, sy = 0.f;
#pragma unroll
    for (int c = 0; c < 4; ++c) {                    // c == lg
        const int off = ((g * 2 + h) * 64 + c * 16 + li) * 8;
        float f[8];
        ushort8_t hi, lo;

        *reinterpret_cast<float4*>(&f[0]) = xr[2 * c];
        *reinterpret_cast<float4*>(&f[4]) = xr[2 * c + 1];
#pragma unroll
        for (int e = 0; e < 8; ++e) {
            sx = fmaf(f[e], f[e], sx);
            const float v2 = 2.f * f[e];             // scale X side by 2
            unsigned short hh = bf16_rne(v2);
            hi[e] = hh;
            lo[e] = bf16_rne(v2 - bf16_val(hh));
        }
        *reinterpret_cast<ushort8_t*>(&Xs[pb + off])         = hi;
        *reinterpret_cast<ushort8_t*>(&Xs[pb + PFRAG + off]) = lo;

        *reinterpret_cast<float4*>(&f[0]) = yr[2 * c];
        *reinterpret_cast<float4*>(&f[4]) = yr[2 * c + 1];
#pragma unroll
        for (int e = 0; e < 8; ++e) {
            sy = fmaf(f[e], f[e], sy);
            unsigned short hh = bf16_rne(f[e]);
            hi[e] = hh;
            lo[e] = bf16_rne(f[e] - bf16_val(hh));
        }
        *reinterpret_cast<ushort8_t*>(&Ys[pb + off])         = hi;
        *reinterpret_cast<ushort8_t*>(&Ys[pb + PFRAG + off]) = lo;
    }
    sx += __shfl_xor(sx, 1);                         // full-row norms
    sy += __shfl_xor(sy, 1);

    // ---- tail frags: thread h writes lg = 2h and 2h+1 chunks ----
    const int tb = 2 * PFRAG + g * 512;
    ushort8_t zc = {0, 0, 0, 0, 0, 0, 0, 0};
    if (h == 0) {
        const unsigned short nx2h = bf16_rne(-sx);
        const unsigned short nx2l = bf16_rne(-sx - bf16_val(nx2h));
        const unsigned short ny2h = bf16_rne(-sy);
        const unsigned short ny2l = bf16_rne(-sy - bf16_val(ny2h));
        ushort8_t xt = {nx2h, nx2l, ONE_BF16, ONE_BF16, 0, 0, 0, 0};
        ushort8_t yt = {ONE_BF16, ONE_BF16, ny2h, ny2l, 0, 0, 0, 0};
        *reinterpret_cast<ushort8_t*>(&Xs[pb + tb + (0 * 16 + li) * 8]) = xt;
        *reinterpret_cast<ushort8_t*>(&Ys[pb + tb + (0 * 16 + li) * 8]) = yt;
        *reinterpret_cast<ushort8_t*>(&Xs[pb + tb + (1 * 16 + li) * 8]) = zc;
        *reinterpret_cast<ushort8_t*>(&Ys[pb + tb + (1 * 16 + li) * 8]) = zc;
    } else {
        *reinterpret_cast<ushort8_t*>(&Xs[pb + tb + (2 * 16 + li) * 8]) = zc;
        *reinterpret_cast<ushort8_t*>(&Ys[pb + tb + (2 * 16 + li) * 8]) = zc;
        *reinterpret_cast<ushort8_t*>(&Xs[pb + tb + (3 * 16 + li) * 8]) = zc;
        *reinterpret_cast<ushort8_t*>(&Ys[pb + tb + (3 * 16 + li) * 8]) = zc;
    }
}

// ---------------------------------------------------------------------------
// Kernel 2: 4-wave blocks, each wave an independent 64x64 tile (no LDS/sync).
// 7 MFMA k-steps: (2Xh.Yh, 2Xl.Yh, 2Xh.Yl) x 2 + norm tail -> acc = -dist2.
// Epilogue: out = exp(min(acc, 0)) -- 2 VALU + 1 trans per element.
// XCD swizzle: xcd = bid&7 owns a 1024-col slab; col-quad held while row
// tiles sweep -> Y panels L2-resident per XCD.
// ---------------------------------------------------------------------------
__global__ void __launch_bounds__(256)
rbf_mfma_kernel(const unsigned short* __restrict__ Xs,
                const unsigned short* __restrict__ Ys,
                float* __restrict__ out) {
    const int tid  = threadIdx.x;
    const int lane = tid & 63;
    const int w    = tid >> 6;

    const int bid   = blockIdx.x;        // 4096 blocks
    const int xcd   = bid & 7;
    const int idx   = bid >> 3;          // 0..511
    const int cquad = xcd * 4 + (idx >> 7);   // 0..31 (256-col quad)
    const int rt    = idx & 127;              // row tile 0..127

    const int ct   = cquad * 4 + w;      // this wave's 64-col tile
    const int row0 = rt * 64;
    const int col0 = ct * 64;
    const unsigned short* Xp = Xs + (size_t)(rt >> 1) * PSTRIDE;
    const unsigned short* Yp = Ys + (size_t)(ct >> 1) * PSTRIDE;
    const int gx0 = (rt & 1) * 4;
    const int gy0 = (ct & 1) * 4;

    floatx4 acc[4][4] = {};

#define GF(P, hl, g, ks)                                                       \
    (*reinterpret_cast<const short8_t*>(                                       \
        (P) + (hl) * PFRAG + (((g) * 2 + (ks)) * 64 + lane) * 8))
#define GT(P, g)                                                               \
    (*reinterpret_cast<const short8_t*>(                                       \
        (P) + 2 * PFRAG + (g) * 512 + lane * 8))

#pragma unroll
    for (int ks = 0; ks < 2; ++ks) {
        short8_t aH[4], bH[4], aL[4], bL[4];
#pragma unroll
        for (int mi = 0; mi < 4; ++mi) aH[mi] = GF(Xp, 0, gx0 + mi, ks);
#pragma unroll
        for (int ni = 0; ni < 4; ++ni) bH[ni] = GF(Yp, 0, gy0 + ni, ks);
#pragma unroll
        for (int mi = 0; mi < 4; ++mi)
#pragma unroll
            for (int ni = 0; ni < 4; ++ni)
                acc[mi][ni] = __builtin_amdgcn_mfma_f32_16x16x32_bf16(
                    bH[ni], aH[mi], acc[mi][ni], 0, 0, 0);   // 2Xh . Yh
#pragma unroll
        for (int ni = 0; ni < 4; ++ni) bL[ni] = GF(Yp, 1, gy0 + ni, ks);
#pragma unroll
        for (int mi = 0; mi < 4; ++mi)
#pragma unroll
            for (int ni = 0; ni < 4; ++ni)
                acc[mi][ni] = __builtin_amdgcn_mfma_f32_16x16x32_bf16(
                    bL[ni], aH[mi], acc[mi][ni], 0, 0, 0);   // 2Xh . Yl
#pragma unroll
        for (int mi = 0; mi < 4; ++mi) aL[mi] = GF(Xp, 1, gx0 + mi, ks);
#pragma unroll
        for (int mi = 0; mi < 4; ++mi)
#pragma unroll
            for (int ni = 0; ni < 4; ++ni)
                acc[mi][ni] = __builtin_amdgcn_mfma_f32_16x16x32_bf16(
                    bH[ni], aL[mi], acc[mi][ni], 0, 0, 0);   // 2Xl . Yh
    }
    {   // ---- norm tail: adds (-x2) + (-y2) ----
        short8_t aT[4], bT[4];
#pragma unroll
        for (int mi = 0; mi < 4; ++mi) aT[mi] = GT(Xp, gx0 + mi);
#pragma unroll
        for (int ni = 0; ni < 4; ++ni) bT[ni] = GT(Yp, gy0 + ni);
#pragma unroll
        for (int mi = 0; mi < 4; ++mi)
#pragma unroll
            for (int ni = 0; ni < 4; ++ni)
                acc[mi][ni] = __builtin_amdgcn_mfma_f32_16x16x32_bf16(
                    bT[ni], aT[mi], acc[mi][ni], 0, 0, 0);
    }
#undef GF
#undef GT

    // ---- epilogue: out = exp(min(-dist2, 0)); non-temporal stores ----
    const int li = lane & 15;
    const int lg = lane >> 4;
#pragma unroll
    for (int mi = 0; mi < 4; ++mi) {
        const int row = row0 + mi * 16 + li;
        float* obase = out + (size_t)row * N_ROWS + col0 + lg * 4;
#pragma unroll
        for (int ni = 0; ni < 4; ++ni) {
            floatx4 o;
            o[0] = __expf(fminf(acc[mi][ni][0], 0.f));
            o[1] = __expf(fminf(acc[mi][ni][1], 0.f));
            o[2] = __expf(fminf(acc[mi][ni][2], 0.f));
            o[3] = __expf(fminf(acc[mi][ni][3], 0.f));
            __builtin_nontemporal_store(o, reinterpret_cast<floatx4*>(obase + ni * 16));
        }
    }
}

// ---------------------------------------------------------------------------
extern "C" void kernel_launch(void* const* d_in, const int* in_sizes, int n_in,
                              void* d_out, int out_size, void* d_ws, size_t ws_size,
                              hipStream_t stream) {
    const float* X = (const float*)d_in[0];
    const float* Y = (const float*)d_in[1];
    float* out = (float*)d_out;

    unsigned short* Xs = (unsigned short*)d_ws;            // 64 x 40 KiB = 2.5 MiB
    unsigned short* Ys = Xs + (size_t)(N_ROWS / 128) * PSTRIDE;

    split_norms_kernel<<<(2 * N_ROWS) / 256, 256, 0, stream>>>(X, Y, Xs, Ys);

    rbf_mfma_kernel<<<4096, 256, 0, stream>>>(Xs, Ys, out);
}

// Round 10
// 84.021 us; speedup vs baseline: 1.4076x; 1.4076x over previous
//
#include <hip/hip_runtime.h>

typedef __attribute__((ext_vector_type(8))) short          short8_t;   // 8 bf16
typedef __attribute__((ext_vector_type(8))) unsigned short ushort8_t;
typedef __attribute__((ext_vector_type(4))) float          floatx4;

constexpr int N_ROWS = 8192;
constexpr int DIM    = 64;
constexpr int PANEL  = 128 * DIM;   // 8192 ushorts = 16 KiB per (panel, hi/lo)

// f32 -> bf16 round-to-nearest-even
__device__ __forceinline__ unsigned short bf16_rne(float f) {
    unsigned int u = __float_as_uint(f);
    u += 0x7FFFu + ((u >> 16) & 1u);
    return (unsigned short)(u >> 16);
}

// ---------------------------------------------------------------------------
// Kernel 1: NEGATED norms + hi/lo bf16 split, written in FRAGMENT order:
//   group g of panel p, k = ks*32 + lg*8 + e:
//   ushort offset in panel-half = ((g*2 + ks)*64 + lg*16 + li)*8 + e
// so a per-(group,ks) fragment load is one contiguous 1-KiB wave load.
// ---------------------------------------------------------------------------
__global__ void __launch_bounds__(256)
split_norms_kernel(const float* __restrict__ X, const float* __restrict__ Y,
                   float* __restrict__ x2n, float* __restrict__ y2n,
                   unsigned short* __restrict__ Xs, unsigned short* __restrict__ Ys) {
    const int t  = blockIdx.x * 256 + threadIdx.x;   // [0, 16384)
    const int r  = t >> 1;                           // row
    const int h  = t & 1;                            // k-half (== ks)
    const int p  = r >> 7;
    const int rl = r & 127;
    const int g  = rl >> 4;
    const int li = rl & 15;
    const size_t pb = (size_t)p * (2 * PANEL);

    const float4* xr = reinterpret_cast<const float4*>(X + (size_t)r * DIM + h * 32);
    const float4* yr = reinterpret_cast<const float4*>(Y + (size_t)r * DIM + h * 32);

    float sx = 0.f, sy = 0.f;
#pragma unroll
    for (int c = 0; c < 4; ++c) {                    // lg = c
        const int off = ((g * 2 + h) * 64 + c * 16 + li) * 8;
        float f[8];
        ushort8_t hi, lo;

        *reinterpret_cast<float4*>(&f[0]) = xr[2 * c];
        *reinterpret_cast<float4*>(&f[4]) = xr[2 * c + 1];
#pragma unroll
        for (int e = 0; e < 8; ++e) {
            sx = fmaf(f[e], f[e], sx);
            unsigned short hh = bf16_rne(f[e]);
            hi[e] = hh;
            lo[e] = bf16_rne(f[e] - __uint_as_float((unsigned int)hh << 16));
        }
        *reinterpret_cast<ushort8_t*>(&Xs[pb + off])         = hi;
        *reinterpret_cast<ushort8_t*>(&Xs[pb + PANEL + off]) = lo;

        *reinterpret_cast<float4*>(&f[0]) = yr[2 * c];
        *reinterpret_cast<float4*>(&f[4]) = yr[2 * c + 1];
#pragma unroll
        for (int e = 0; e < 8; ++e) {
            sy = fmaf(f[e], f[e], sy);
            unsigned short hh = bf16_rne(f[e]);
            hi[e] = hh;
            lo[e] = bf16_rne(f[e] - __uint_as_float((unsigned int)hh << 16));
        }
        *reinterpret_cast<ushort8_t*>(&Ys[pb + off])         = hi;
        *reinterpret_cast<ushort8_t*>(&Ys[pb + PANEL + off]) = lo;
    }
    sx += __shfl_xor(sx, 1);
    sy += __shfl_xor(sy, 1);
    if (h == 0) { x2n[r] = -sx; y2n[r] = -sy; }      // negated norms
}

// ---------------------------------------------------------------------------
// Kernel 2: one wave per 64x64 output tile. NO LDS, NO barrier.
// Identical to the 73.4-us R7 kernel EXCEPT: B-fragments are loaded per-ni
// inside the MFMA loop (live range 8 VGPR instead of 32) and the kernel is
// capped at 128 VGPR via __launch_bounds__(64, 4) -> 4 waves/SIMD instead
// of 2 (occupancy cliff at 128 regs, m69). Single-variable occupancy probe.
// ---------------------------------------------------------------------------
__global__ void __launch_bounds__(64, 4)
rbf_mfma_kernel(const unsigned short* __restrict__ Xs,
                const unsigned short* __restrict__ Ys,
                const float* __restrict__ x2n, const float* __restrict__ y2n,
                float* __restrict__ out) {
    const int lane = threadIdx.x;
    const int row0 = blockIdx.y * 64;
    const int col0 = blockIdx.x * 64;
    const unsigned short* Xp = Xs + (size_t)(blockIdx.y >> 1) * (2 * PANEL);
    const unsigned short* Yp = Ys + (size_t)(blockIdx.x >> 1) * (2 * PANEL);
    const int gx0 = (blockIdx.y & 1) * 4;   // A row-groups gx0..gx0+3
    const int gy0 = (blockIdx.x & 1) * 4;   // B col-groups gy0..gy0+3

    floatx4 acc[4][4] = {};

#define GF(P, hl, g, ks)                                                       \
    (*reinterpret_cast<const short8_t*>(                                       \
        (P) + (hl) * PANEL + (((g) * 2 + (ks)) * 64 + lane) * 8))

#pragma unroll
    for (int ks = 0; ks < 2; ++ks) {
        short8_t aH[4], aL[4];
#pragma unroll
        for (int mi = 0; mi < 4; ++mi) aH[mi] = GF(Xp, 0, gx0 + mi, ks);
#pragma unroll
        for (int mi = 0; mi < 4; ++mi) aL[mi] = GF(Xp, 1, gx0 + mi, ks);
#pragma unroll
        for (int ni = 0; ni < 4; ++ni) {
            const short8_t bH = GF(Yp, 0, gy0 + ni, ks);
            const short8_t bL = GF(Yp, 1, gy0 + ni, ks);
#pragma unroll
            for (int mi = 0; mi < 4; ++mi) {
                acc[mi][ni] = __builtin_amdgcn_mfma_f32_16x16x32_bf16(
                    bH, aH[mi], acc[mi][ni], 0, 0, 0);   // Xh . Yh
                acc[mi][ni] = __builtin_amdgcn_mfma_f32_16x16x32_bf16(
                    bL, aH[mi], acc[mi][ni], 0, 0, 0);   // Xh . Yl
                acc[mi][ni] = __builtin_amdgcn_mfma_f32_16x16x32_bf16(
                    bH, aL[mi], acc[mi][ni], 0, 0, 0);   // Xl . Yh
            }
        }
    }
#undef GF

    // ---- epilogue: lane (li,lg) reg j -> out[row0+mi*16+li][col0+ni*16+lg*4+j]
    // out = exp(min(2*xy + (-x2) + (-y2), 0)); non-temporal full-line stores.
    const int li = lane & 15;
    const int lg = lane >> 4;
    const int orow = row0 + li;
    const int ocol = col0 + lg * 4;
#pragma unroll
    for (int mi = 0; mi < 4; ++mi) {
        const float xs = x2n[orow + mi * 16];
        float* obase = out + (size_t)(orow + mi * 16) * N_ROWS + ocol;
#pragma unroll
        for (int ni = 0; ni < 4; ++ni) {
            const float4 yv = *reinterpret_cast<const float4*>(&y2n[ocol + ni * 16]);
            floatx4 o;
            o[0] = __expf(fminf(fmaf(2.f, acc[mi][ni][0], xs + yv.x), 0.f));
            o[1] = __expf(fminf(fmaf(2.f, acc[mi][ni][1], xs + yv.y), 0.f));
            o[2] = __expf(fminf(fmaf(2.f, acc[mi][ni][2], xs + yv.z), 0.f));
            o[3] = __expf(fminf(fmaf(2.f, acc[mi][ni][3], xs + yv.w), 0.f));
            __builtin_nontemporal_store(o, reinterpret_cast<floatx4*>(obase + ni * 16));
        }
    }
}

// ---------------------------------------------------------------------------
extern "C" void kernel_launch(void* const* d_in, const int* in_sizes, int n_in,
                              void* d_out, int out_size, void* d_ws, size_t ws_size,
                              hipStream_t stream) {
    const float* X = (const float*)d_in[0];
    const float* Y = (const float*)d_in[1];
    float* out = (float*)d_out;

    float* x2n = (float*)d_ws;                             // 8192 f32 (negated)
    float* y2n = x2n + N_ROWS;                             // 8192 f32 (negated)
    unsigned short* Xs = (unsigned short*)(y2n + N_ROWS);  // 2 MiB
    unsigned short* Ys = Xs + (N_ROWS / 128) * 2 * PANEL;  // 2 MiB

    split_norms_kernel<<<(2 * N_ROWS) / 256, 256, 0, stream>>>(X, Y, x2n, y2n, Xs, Ys);

    dim3 grid(N_ROWS / 64, N_ROWS / 64);   // 128 x 128 one-wave blocks
    rbf_mfma_kernel<<<grid, 64, 0, stream>>>(Xs, Ys, x2n, y2n, out);
}